// Round 8
// baseline (21958.669 us; speedup 1.0000x reference)
//
#include <hip/hip_runtime.h>

// LSTM b=32, t=1024, din=512, hid=1024. Persistent cooperative kernel.
//
// R11 = R10 with the xst write-collision BUG FIXED + hardened escalation.
// R10 bug: xround K-split had all 8 waves overwrite the same xst cells
// (no wave dim) -> x.W kept only one wave's 64-wide k-slice. Fix: COLUMN
// split -- each wave computes only nf == w over the FULL K=512 (16 MFMAs),
// writes xst[buf][kq][r][w][lrow]: disjoint, no cross-wave sum needed.
//
// Structure (unchanged from R10):
// 256 blocks = 8 systems x 32 members. System g = bk&7 (round-robin ->
// co-resident on one XCD; PERF assumption only). System owns batches
// [4g,4g+4); member m = bk>>3 owns units [32m,32m+32).
//  - h exchange: f32 tagged in mantissa LSB. Publish = double store sc0+sc1
//    (same value -> any interleaving safe; sc1 keeps L3 fresh for any
//    cross-XCD reader). Poll with sc0; escalate to sc1: in-step after 256
//    empty rounds, chronically via badness accumulator (livelock-proof
//    under ANY block->XCD mapping; worst case = R6-like speed).
//  - ABA: slot=t&1, tag=(t>>1)&1. Skew<=1: consume(v) spans all 32 members
//    across the 8 waves, so no member passes barrier A(t+1) until every
//    member published v(t+1) -> slot of v(t) can't be overwritten (next
//    writer is v(t+2)).
//  - x-part every 4 steps: MFMA rows = 4 batches x 4 future steps, W-x
//    streamed (off critical path), result in LDS ping-pong.
//  - W-h register-resident (32 frags = 128 VGPR). ONE barrier/step.

#define T_STEPS 1024
#define BATCH   32
#define DIN     512
#define HID     1024
#define KTOT    1536
#define NBLK    256
#define NSYS    8
#define HSYS    4096          // f32 words per system per slot: 4 b x 1024 u
#define HSLOT   (NSYS*HSYS)   // 32768 words per slot

typedef __attribute__((ext_vector_type(8))) short  short8;
typedef __attribute__((ext_vector_type(4))) float  floatx4;
typedef __attribute__((ext_vector_type(4))) unsigned int uintx4;
typedef __attribute__((ext_vector_type(4))) unsigned short ushort4_;

#define MFMA16(a,b,c) __builtin_amdgcn_mfma_f32_16x16x32_bf16(a, b, c, 0, 0, 0)

__device__ __forceinline__ unsigned short f2bf(float f) {
    unsigned u = __builtin_bit_cast(unsigned, f);
    u += 0x7FFFu + ((u >> 16) & 1u);
    return (unsigned short)(u >> 16);
}
__device__ __forceinline__ float sigf(float x) { return 1.f / (1.f + __expf(-x)); }
__device__ __forceinline__ float tanh_fast(float x) {
    float e = __expf(2.f * x);
    return 1.f - 2.f / (e + 1.f);
}
__device__ __forceinline__ unsigned cvt2(float a, float b) {
    unsigned r;
    asm("v_cvt_pk_bf16_f32 %0, %1, %2" : "=v"(r) : "v"(a), "v"(b));
    return r;
}
__device__ __forceinline__ floatx4 exch_load(const float* p, bool dev) {
    floatx4 v;
    if (dev) asm volatile("global_load_dwordx4 %0, %1, off sc1" : "=v"(v) : "v"(p));
    else     asm volatile("global_load_dwordx4 %0, %1, off sc0" : "=v"(v) : "v"(p));
    return v;
}
__device__ __forceinline__ void publish_store(unsigned* p, unsigned v) {
    asm volatile("global_store_dword %0, %1, off sc0\n\t"
                 "global_store_dword %0, %1, off sc1" :: "v"(p), "v"(v) : "memory");
}
__device__ __forceinline__ void wait_vm0() {
    asm volatile("s_waitcnt vmcnt(0)" ::: "memory");
}

// ---- prep: kernel [1536][4096] fp32 -> wt [4096 cols][1536 k] bf16 ----
__global__ __launch_bounds__(256) void prep_wt(const float* __restrict__ kern,
                                               unsigned short* __restrict__ wt) {
    __shared__ unsigned short tile[64][72];
    const int c0 = (blockIdx.x & 63) * 64;
    const int k0 = (blockIdx.x >> 6) * 64;
    const int cl = threadIdx.x & 63;
    const int kg = threadIdx.x >> 6;
    #pragma unroll
    for (int i = 0; i < 16; ++i) {
        int kl = kg * 16 + i;
        tile[cl][kl] = f2bf(kern[(k0 + kl) * 4096 + c0 + cl]);
    }
    __syncthreads();
    #pragma unroll
    for (int i = 0; i < 16; ++i) {
        int cc = kg * 16 + i;
        wt[(size_t)(c0 + cc) * KTOT + k0 + cl] = tile[cc][cl];
    }
}

// ---- prep: x [32][1024][512] fp32 -> xT [1024][32][512] bf16 ----
__global__ __launch_bounds__(256) void prep_x(const float* __restrict__ x,
                                              unsigned short* __restrict__ xT) {
    const int row = blockIdx.x * 2 + (threadIdx.x >> 7);
    const int l   = threadIdx.x & 127;
    const int b = row >> 10, t = row & 1023;
    float4 v = ((const float4*)(x + (size_t)row * DIN))[l];
    ushort4_ o;
    o.x = f2bf(v.x); o.y = f2bf(v.y); o.z = f2bf(v.z); o.w = f2bf(v.w);
    *(ushort4_*)(xT + ((size_t)t * BATCH + b) * DIN + l * 4) = o;
}

// ---- prep: v0 (tag0) into slot0 for all systems; slot1 poisoned stale ----
__global__ __launch_bounds__(256) void init_h(const float* __restrict__ h_init,
                                              unsigned* __restrict__ hbuf_u) {
    const int idx = blockIdx.x * 256 + threadIdx.x;   // 0..32767
    const int u = idx & 1023;
    hbuf_u[idx] = __builtin_bit_cast(unsigned, h_init[u]) & ~1u;  // v0, tag 0
    hbuf_u[HSLOT + idx] = 1u;                                     // v1 poison
}

// ---- persistent LSTM ----
__global__ __launch_bounds__(512, 2) void lstm_persist(
    const unsigned short* __restrict__ wt,   // [4096 cols][1536 k] bf16
    const unsigned short* __restrict__ xT,   // [1024][32][512] bf16
    float* __restrict__ hbuf,                // [2][8 sys][4 b][1024 u] f32 tagged
    const float* __restrict__ bias,          // [4096]
    float* __restrict__ out)                 // [32][1024][1024] fp32
{
    __shared__ float red[2][8][4][8][17];    // 34,816 B: [pp][kwave][b][nf][16+1]
    __shared__ float xst[2][4][4][8][17];    // 17,408 B: [pp][tf][b][nf][16+1]

    const int bk   = blockIdx.x;
    const int g    = bk & 7;       // system (XCD-aligned if round-robin holds)
    const int m    = bk >> 3;      // member 0..31: units [32m, 32m+32)
    const int tid  = threadIdx.x;
    const int w    = tid >> 6;     // wave 0..7
    const int lane = tid & 63;
    const int lrow = lane & 15;
    const int kq   = lane >> 4;
    const int b4   = lrow & 3;     // batch row (consume: rows replicate 0-3)

    unsigned* hbuf_u = (unsigned*)hbuf;

    // global W-col of local col (nf*16 + lrow): gate = nf>>1
    int gcolv[8];
    #pragma unroll
    for (int nf = 0; nf < 8; ++nf)
        gcolv[nf] = (nf >> 1) * HID + m * 32 + ((nf & 1) << 4) + lrow;

    // ---- resident h-part weights: 32 frags = 128 VGPR ----
    short8 wbh[4][8];
    #pragma unroll
    for (int ks = 0; ks < 4; ++ks)
        #pragma unroll
        for (int nf = 0; nf < 8; ++nf)
            wbh[ks][nf] = *(const short8*)(wt + (size_t)gcolv[nf] * KTOT
                                           + 512 + w * 128 + ks * 32 + kq * 8);

    // pointwise mapping (tid<128): batch pb (0..3), unit loc (0..31)
    const int pb = tid >> 5;
    const int loc = tid & 31;
    float bias_r[4], c_state = 0.f;
    if (tid < 128) {
        #pragma unroll
        for (int g2 = 0; g2 < 4; ++g2)
            bias_r[g2] = bias[g2 * HID + m * 32 + loc];
    }

    bool dev = false;   // sticky per-wave escalation: false = sc0 fast path
    int badness = 0;    // chronic cross-XCD detector

    // x-round (COLUMN-SPLIT, bug fix): this wave computes ONLY nf == w over
    // the FULL K=512 for steps t0..t0+3. A rows = (tf=lrow>>2, b=lrow&3);
    // C row 4*kq+r -> (tf=kq, b=r). Writes xst[buf][kq][r][w][lrow]:
    // disjoint across waves -> no collision, no cross-wave sum needed.
    auto xround = [&](int t0, int buf) {
        const floatx4 zero = {0.f, 0.f, 0.f, 0.f};
        floatx4 acc2 = zero;
        const size_t wc = (size_t)gcolv[w] * KTOT;
        #pragma unroll
        for (int ks2 = 0; ks2 < 16; ++ks2) {
            short8 xa = *(const short8*)(xT
                + ((size_t)(t0 + (lrow >> 2)) * BATCH + g * 4 + b4) * DIN
                + ks2 * 32 + kq * 8);
            short8 wx = *(const short8*)(wt + wc + ks2 * 32 + kq * 8);
            acc2 = MFMA16(xa, wx, acc2);
        }
        #pragma unroll
        for (int r = 0; r < 4; ++r)
            xst[buf][kq][r][w][lrow] = acc2[r];
    };

    xround(0, 0);   // prologue: x-part for steps 0..3

    for (int t = 0; t < T_STEPS; ++t) {
        // ================= consume v(t): poll + cvt + h-MFMA ================
        {
            const int slot = t & 1;
            const unsigned tg = ((unsigned)t >> 1) & 1u;
            const float* hb = hbuf + (size_t)slot * HSLOT + g * HSYS
                            + b4 * 1024 + w * 128 + kq * 8;
            floatx4 hf[4][2];
            #pragma unroll
            for (int ks = 0; ks < 4; ++ks) {
                hf[ks][0] = exch_load(hb + ks * 32, dev);
                hf[ks][1] = exch_load(hb + ks * 32 + 4, dev);
            }
            wait_vm0();
            __builtin_amdgcn_sched_barrier(0);
            unsigned stale = 0;
            #pragma unroll
            for (int ks = 0; ks < 4; ++ks) {
                uintx4 u = __builtin_bit_cast(uintx4, hf[ks][0]);
                uintx4 v = __builtin_bit_cast(uintx4, hf[ks][1]);
                unsigned fr = tg ? (u[0] & u[1] & u[2] & u[3] & v[0] & v[1] & v[2] & v[3])
                                 : ~(u[0] | u[1] | u[2] | u[3] | v[0] | v[1] | v[2] | v[3]);
                if (!(fr & 1u)) stale |= 1u << ks;
            }
            int rounds = 0;
            while (__any((int)(stale != 0u))) {
                ++rounds;
                if (rounds > 256) dev = true;           // in-step escalation
                if (rounds > 8) __builtin_amdgcn_s_sleep(2);
                #pragma unroll
                for (int ks = 0; ks < 4; ++ks)
                    if (stale & (1u << ks)) {
                        hf[ks][0] = exch_load(hb + ks * 32, dev);
                        hf[ks][1] = exch_load(hb + ks * 32 + 4, dev);
                    }
                wait_vm0();
                __builtin_amdgcn_sched_barrier(0);
                unsigned ns = 0;
                #pragma unroll
                for (int ks = 0; ks < 4; ++ks)
                    if (stale & (1u << ks)) {
                        uintx4 u = __builtin_bit_cast(uintx4, hf[ks][0]);
                        uintx4 v = __builtin_bit_cast(uintx4, hf[ks][1]);
                        unsigned fr = tg ? (u[0] & u[1] & u[2] & u[3] & v[0] & v[1] & v[2] & v[3])
                                         : ~(u[0] | u[1] | u[2] | u[3] | v[0] | v[1] | v[2] | v[3]);
                        if (!(fr & 1u)) ns |= 1u << ks;
                    }
                stale = ns;
            }
            if (rounds > 4) {                            // chronic escalation
                badness += rounds;
                if (badness > 16384) dev = true;
            }
            const floatx4 zero = {0.f, 0.f, 0.f, 0.f};
            floatx4 acc[8] = {zero, zero, zero, zero, zero, zero, zero, zero};
            #pragma unroll
            for (int ks = 0; ks < 4; ++ks) {
                union { short8 s; unsigned u[4]; } wa;
                wa.u[0] = cvt2(hf[ks][0][0], hf[ks][0][1]);
                wa.u[1] = cvt2(hf[ks][0][2], hf[ks][0][3]);
                wa.u[2] = cvt2(hf[ks][1][0], hf[ks][1][1]);
                wa.u[3] = cvt2(hf[ks][1][2], hf[ks][1][3]);
                #pragma unroll
                for (int nf = 0; nf < 8; ++nf)
                    acc[nf] = MFMA16(wa.s, wbh[ks][nf], acc[nf]);
            }
            // C rows replicate batches (A rows = b4) -> kq group q extracts
            // nf {2q, 2q+1}; all 8 nf covered across the 4 kq groups.
            #pragma unroll
            for (int j = 0; j < 2; ++j)
                #pragma unroll
                for (int r = 0; r < 4; ++r)
                    red[t & 1][w][r][2 * kq + j][lrow] = acc[2 * kq + j][r];
        }

        __syncthreads();    // A(t): red[t&1] complete; xst(t) visible

        // ================= pointwise + publish + out (waves 0-1) ============
        if (tid < 128) {
            const int bufx = (t >> 2) & 1, tf = t & 3;
            const int nfh = loc >> 4, e = loc & 15;
            float gv[4];
            #pragma unroll
            for (int g2 = 0; g2 < 4; ++g2) {
                float s = bias_r[g2] + xst[bufx][tf][pb][g2 * 2 + nfh][e];
                #pragma unroll
                for (int s8 = 0; s8 < 8; ++s8)
                    s += red[t & 1][s8][pb][g2 * 2 + nfh][e];
                gv[g2] = s;
            }
            const float fg = sigf(gv[0]);
            const float ig = sigf(gv[1]);
            const float og = sigf(gv[2]);
            const float gg = tanh_fast(gv[3]);
            c_state = fg * c_state + ig * gg;
            const float hn = og * tanh_fast(c_state);

            if (t + 1 < T_STEPS) {
                unsigned hv = (__builtin_bit_cast(unsigned, hn) & ~1u)
                            | (((unsigned)(t + 1) >> 1) & 1u);
                publish_store(hbuf_u + (size_t)((t + 1) & 1) * HSLOT + g * HSYS
                              + pb * 1024 + m * 32 + loc, hv);
            }
            out[(size_t)(g * 4 + pb) * (T_STEPS * HID) + (size_t)t * HID
                + m * 32 + loc] = hn;
        }

        // ========== x-round for steps t+1..t+4 (poll-shadow work) ===========
        if ((t & 3) == 3 && t + 1 < T_STEPS)
            xround(t + 1, ((t + 1) >> 2) & 1);
    }
}

extern "C" void kernel_launch(void* const* d_in, const int* in_sizes, int n_in,
                              void* d_out, int out_size, void* d_ws, size_t ws_size,
                              hipStream_t stream) {
    (void)in_sizes; (void)n_in; (void)out_size;
    const float* x      = (const float*)d_in[0];
    // d_in[1] = input_paddings (all zero, unused per reference)
    const float* kern   = (const float*)d_in[2];
    const float* bias   = (const float*)d_in[3];
    const float* h_init = (const float*)d_in[4];
    float* out = (float*)d_out;

    char* ws = (char*)d_ws;
    unsigned short* wt   = (unsigned short*)(ws);                       // 12,582,912 B
    unsigned short* xT   = (unsigned short*)(ws + 12582912);            // 33,554,432 B
    float*          hbuf = (float*)(ws + 12582912 + 33554432);          //    262,144 B
    (void)ws_size;

    prep_wt<<<dim3(64 * 24), dim3(256), 0, stream>>>(kern, wt);
    prep_x<<<dim3(BATCH * T_STEPS / 2), dim3(256), 0, stream>>>(x, xT);
    init_h<<<dim3(128), dim3(256), 0, stream>>>(h_init, (unsigned*)hbuf);

    void* args[] = { &wt, &xT, &hbuf, &bias, &out };
    hipLaunchCooperativeKernel((const void*)lstm_persist, dim3(NBLK), dim3(512),
                               args, 0, stream);
}

// Round 9
// 4281.496 us; speedup vs baseline: 5.1287x; 5.1287x over previous
//
#include <hip/hip_runtime.h>

// LSTM b=32, t=1024, din=512, hid=1024. Persistent cooperative kernel.
//
// R12 = R6's PROVEN flag+ack handshake & wave specialization, on R8's
// PROVEN batch-split geometry, with bf16 transport and one barrier/step.
//  - 128 blocks = 2 independent systems x 64 members (batch halves of 16).
//    Block (p,ug) owns 16 batches x 16 units (64 gate cols); M=16 MFMA.
//  - Broadcast per step: 2 sys x 32KB = 4MB (R6: 8MB; R7 fail: 16-48MB).
//  - G waves 0-3: gather->pointwise->publish(bf16, per-wave 4-batch slice)
//    ->x-MFMA(t+1) hidden under the ack->vmcnt(0)->sub-flag->out->prefetch.
//  - H waves 4-7: poll 16 producers' sub-flag lines (dwordx4 each, 4
//    lanes/producer redundant)->bulk 8x16B sc1 h-load->h-MFMA(t+1).
//  - ONE barrier/step: red ping-pong [2][8][16][RSTR]. G reads red[t&1]
//    (written pre-A(t)); all waves write red[(t+1)&1] post-A(t). The buffer
//    G read at t-1 is rewritten only post-A(t): program order within G
//    guarantees its reads finished before it reached A(t). Safe.
//  - Slot overwrite safety (hbuf [2] ping-pong): P publishes v(t+2) only
//    after consuming v(t+1), which needs EVERY block's flag(t+1), which
//    each block sets only after consuming v(t). So all v(t) reads precede
//    any v(t+2) write. Flags are monotone ints (no ABA).
//  - XCD/L2 lessons applied: sc1-only exchange (R11 falsified sc0 polls:
//    no cross-XCD invalidation; sc0+sc1 double-store punched to HBM).

#define T_STEPS 1024
#define BATCH   32
#define DIN     512
#define HID     1024
#define KTOT    1536
#define NBLK    128
#define RSTR    68            // f32 row stride in red: writes 2-way, gather <=4-way
#define REDW    (16*RSTR)     // floats per wave slot (1088; %32==0, slot-invariant)
#define NSLOT   8
#define HSLOT   32768         // shorts per slot: [32 batch rows][1024 units]
#define FLAGSTR 16            // ints per block flag line (64B); [0..3] sub-flags
#define LDS_RED_BYTES (2*NSLOT*REDW*4)           // 139,264
#define LDS_TOTAL     (LDS_RED_BYTES + 512)      // + hLDS

typedef __attribute__((ext_vector_type(8))) short  short8;
typedef __attribute__((ext_vector_type(4))) float  floatx4;
typedef __attribute__((ext_vector_type(4))) int    intx4;
typedef __attribute__((ext_vector_type(4))) unsigned short ushort4_;

#define MFMA16(a,b,c) __builtin_amdgcn_mfma_f32_16x16x32_bf16(a, b, c, 0, 0, 0)

__device__ __forceinline__ unsigned short f2bf(float f) {
    unsigned u = __builtin_bit_cast(unsigned, f);
    u += 0x7FFFu + ((u >> 16) & 1u);
    return (unsigned short)(u >> 16);
}
__device__ __forceinline__ float sigf(float x) { return 1.f / (1.f + __expf(-x)); }
__device__ __forceinline__ float tanh_fast(float x) {
    float e = __expf(2.f * x);
    return 1.f - 2.f / (e + 1.f);
}

// ---- device-scope (L3 coherence point) helpers: sc1 only ----
__device__ __forceinline__ short8 coh_load16(const void* p) {
    short8 v;
    asm volatile("global_load_dwordx4 %0, %1, off sc1" : "=v"(v) : "v"(p));
    return v;
}
__device__ __forceinline__ intx4 coh_load16i(const void* p) {
    intx4 v;
    asm volatile("global_load_dwordx4 %0, %1, off sc1\n\ts_waitcnt vmcnt(0)"
                 : "=v"(v) : "v"(p) : "memory");
    return v;
}
__device__ __forceinline__ void coh_store16(void* p, short8 v) {
    asm volatile("global_store_dwordx4 %0, %1, off sc1" :: "v"(p), "v"(v) : "memory");
}
__device__ __forceinline__ void coh_store4(void* p, int v) {
    asm volatile("global_store_dword %0, %1, off sc1" :: "v"(p), "v"(v) : "memory");
}
__device__ __forceinline__ void wait_vm0() {
    asm volatile("s_waitcnt vmcnt(0)" ::: "memory");
}

// ---- prep: kernel [1536][4096] fp32 -> wt [4096 cols][1536 k] bf16 ----
__global__ __launch_bounds__(256) void prep_wt(const float* __restrict__ kern,
                                               unsigned short* __restrict__ wt) {
    __shared__ unsigned short tile[64][72];
    const int c0 = (blockIdx.x & 63) * 64;
    const int k0 = (blockIdx.x >> 6) * 64;
    const int cl = threadIdx.x & 63;
    const int kg = threadIdx.x >> 6;
    #pragma unroll
    for (int i = 0; i < 16; ++i) {
        int kl = kg * 16 + i;
        tile[cl][kl] = f2bf(kern[(k0 + kl) * 4096 + c0 + cl]);
    }
    __syncthreads();
    #pragma unroll
    for (int i = 0; i < 16; ++i) {
        int cc = kg * 16 + i;
        wt[(size_t)(c0 + cc) * KTOT + k0 + cl] = tile[cc][cl];
    }
}

// ---- prep: x [32][1024][512] fp32 -> xT [1024][32][512] bf16 ----
__global__ __launch_bounds__(256) void prep_x(const float* __restrict__ x,
                                              unsigned short* __restrict__ xT) {
    const int row = blockIdx.x * 2 + (threadIdx.x >> 7);
    const int l   = threadIdx.x & 127;
    const int b = row >> 10, t = row & 1023;
    float4 v = ((const float4*)(x + (size_t)row * DIN))[l];
    ushort4_ o;
    o.x = f2bf(v.x); o.y = f2bf(v.y); o.z = f2bf(v.z); o.w = f2bf(v.w);
    *(ushort4_*)(xT + ((size_t)t * BATCH + b) * DIN + l * 4) = o;
}

// ---- prep: h0 bf16 -> slot0 [32][1024]; zero flags ----
__global__ __launch_bounds__(256) void init_h(const float* __restrict__ h_init,
                                              unsigned short* __restrict__ hbuf,
                                              int* __restrict__ flags) {
    if (blockIdx.x == 32) {
        for (int i = threadIdx.x; i < NBLK * FLAGSTR; i += 256) flags[i] = 0;
        return;
    }
    const int gb = blockIdx.x;                 // global batch row
    for (int u = threadIdx.x; u < HID; u += 256)
        hbuf[gb * HID + u] = f2bf(h_init[u]);
}

// ---- persistent LSTM ----
__global__ __launch_bounds__(512, 1) void lstm_persist(
    const unsigned short* __restrict__ wt,   // [4096 cols][1536 k] bf16
    const unsigned short* __restrict__ xT,   // [1024][32][512] bf16
    unsigned short* __restrict__ hbuf,       // [2][32][1024] bf16
    int* __restrict__ flags,                 // [128*FLAGSTR]; [bk*16+w] subflags
    const float* __restrict__ bias,          // [4096]
    float* __restrict__ out)                 // [32][1024][1024] fp32
{
    extern __shared__ char smem[];
    float* red = (float*)smem;                              // [2][8][REDW]
    unsigned short* hLDS = (unsigned short*)(smem + LDS_RED_BYTES); // [16][16]

    const int bk   = blockIdx.x;
    const int p    = bk >> 6;      // batch half (independent system)
    const int ug   = bk & 63;      // unit group: units [ug*16, ug*16+16)
    const int tid  = threadIdx.x;
    const int w    = tid >> 6;     // wave 0..7
    const int lane = tid & 63;
    const int lrow = lane & 15;
    const int kq   = lane >> 4;
    const bool isG = w < 4;
    const int  sl  = w & 3;        // G: x k-slice; H: h k-slice

    // ---- persistent weights in registers (nf IS the gate index) ----
    // G wave sl: x-k = sl*128 + i*32 + kq*8 (i<4).  H wave sl: h-k =
    // 512 + sl*256 + j*32 + kq*8 (j<8). Col = nf*HID + ug*16 + lrow.
    short8 wb[8][4];
    if (isG) {
        #pragma unroll
        for (int nf = 0; nf < 4; ++nf) {
            const size_t gcol = (size_t)(nf * HID + ug * 16 + lrow) * KTOT;
            #pragma unroll
            for (int i = 0; i < 4; ++i)
                wb[i][nf] = *(const short8*)(wt + gcol + sl * 128 + i * 32 + kq * 8);
        }
    } else {
        #pragma unroll
        for (int nf = 0; nf < 4; ++nf) {
            const size_t gcol = (size_t)(nf * HID + ug * 16 + lrow) * KTOT;
            #pragma unroll
            for (int j = 0; j < 8; ++j)
                wb[j][nf] = *(const short8*)(wt + gcol + 512 + sl * 256 + j * 32 + kq * 8);
        }
    }

    // pointwise mapping (tid<256): batch pb (0..15), unit pu (0..15)
    const int pb = tid >> 4;
    const int pu = tid & 15;
    float bias_r[4], c_state = 0.f;
    if (tid < 256) {
        #pragma unroll
        for (int g = 0; g < 4; ++g) bias_r[g] = bias[g * HID + ug * 16 + pu];
    }

    // H: flag line of producer (lane&15) of this wave's 16-producer set
    const int* fp = flags + (p * 64 + sl * 16 + (lane & 15)) * FLAGSTR;
    // H: h source offset within a slot (shorts): row p*16+lrow, k sl*256+kq*8
    const int hoff = (p * 16 + lrow) * HID + sl * 256 + kq * 8;

    floatx4 xa[4];

    // ---- prologue: red[0] slots for t=0; G prefetches x(1) ----
    {
        const floatx4 zero = {0.f, 0.f, 0.f, 0.f};
        floatx4 acc[4] = {zero, zero, zero, zero};
        if (isG) {
            const unsigned short* xb = xT + (size_t)(p * 16 + lrow) * DIN;  // t=0
            #pragma unroll
            for (int i = 0; i < 4; ++i) {
                short8 a = *(const short8*)(xb + sl * 128 + i * 32 + kq * 8);
                #pragma unroll
                for (int nf = 0; nf < 4; ++nf) acc[nf] = MFMA16(a, wb[i][nf], acc[nf]);
            }
            const unsigned short* xn = xT + ((size_t)BATCH + p * 16 + lrow) * DIN;
            #pragma unroll
            for (int i = 0; i < 4; ++i)
                xa[i] = *(const floatx4*)(xn + sl * 128 + i * 32 + kq * 8);
        } else {
            short8 ha[8];
            #pragma unroll
            for (int j = 0; j < 8; ++j)
                ha[j] = coh_load16(hbuf + hoff + j * 32);
            wait_vm0();
            __builtin_amdgcn_sched_barrier(0);
            #pragma unroll
            for (int j = 0; j < 8; ++j)
                #pragma unroll
                for (int nf = 0; nf < 4; ++nf) acc[nf] = MFMA16(ha[j], wb[j][nf], acc[nf]);
        }
        #pragma unroll
        for (int nf = 0; nf < 4; ++nf)
            #pragma unroll
            for (int r = 0; r < 4; ++r)
                red[w * REDW + (kq * 4 + r) * RSTR + nf * 16 + lrow] = acc[nf][r];
    }

    for (int t = 0; t < T_STEPS; ++t) {
        __syncthreads();    // A(t): red[t&1] complete (the only barrier/step)

        const float* rc = red + (size_t)(t & 1) * NSLOT * REDW;
        float*       rn = red + (size_t)((t + 1) & 1) * NSLOT * REDW;
        const int    so = ((t + 1) & 1) * HSLOT;

        if (tid < 256) {
            // ---- G: gather 8 slots x 4 gates, activate ----
            float gv[4];
            #pragma unroll
            for (int g = 0; g < 4; ++g) {
                float s = bias_r[g];
                #pragma unroll
                for (int s8 = 0; s8 < 8; ++s8)
                    s += rc[s8 * REDW + pb * RSTR + g * 16 + pu];
                gv[g] = s;
            }
            const float fg = sigf(gv[0]);
            const float ig = sigf(gv[1]);
            const float og = sigf(gv[2]);
            const float gg = tanh_fast(gv[3]);
            c_state = fg * c_state + ig * gg;
            const float hn = og * tanh_fast(c_state);

            if (t + 1 < T_STEPS) {
                // publish own 4-batch slice (wave-local gather, no barrier)
                hLDS[tid] = f2bf(hn);
                asm volatile("s_waitcnt lgkmcnt(0)" ::: "memory");
                if (lane < 8) {
                    const int b = sl * 4 + (lane >> 1), hf2 = lane & 1;
                    short8 v = *(const short8*)(hLDS + sl * 64 + (lane >> 1) * 16 + hf2 * 8);
                    coh_store16(hbuf + so + (p * 16 + b) * HID + ug * 16 + hf2 * 8, v);
                }
                // hide the ack under x-part MFMA for t+1 (register-only)
                const floatx4 zero = {0.f, 0.f, 0.f, 0.f};
                floatx4 acc[4] = {zero, zero, zero, zero};
                #pragma unroll
                for (int i = 0; i < 4; ++i) {
                    short8 a = __builtin_bit_cast(short8, xa[i]);
                    #pragma unroll
                    for (int nf = 0; nf < 4; ++nf) acc[nf] = MFMA16(a, wb[i][nf], acc[nf]);
                }
                #pragma unroll
                for (int nf = 0; nf < 4; ++nf)
                    #pragma unroll
                    for (int r = 0; r < 4; ++r)
                        rn[w * REDW + (kq * 4 + r) * RSTR + nf * 16 + lrow] = acc[nf][r];
                wait_vm0();    // this wave's 128B h-slice acked at L3
                if (lane == 0)
                    coh_store4(flags + bk * FLAGSTR + sl, t + 1);
            }
            // off the handshake path
            out[(size_t)(p * 16 + pb) * (T_STEPS * HID) + (size_t)t * HID
                + ug * 16 + pu] = hn;
            if (t + 2 < T_STEPS) {
                const unsigned short* xn =
                    xT + ((size_t)(t + 2) * BATCH + p * 16 + lrow) * DIN;
                #pragma unroll
                for (int i = 0; i < 4; ++i)
                    xa[i] = *(const floatx4*)(xn + sl * 128 + i * 32 + kq * 8);
            }
        } else if (t + 1 < T_STEPS) {
            // ---- H: poll 16 producers' sub-flag lines ----
            const int tgt = t + 1;
            while (true) {
                intx4 f = coh_load16i(fp);
                bool ok = (f.x >= tgt) & (f.y >= tgt) & (f.z >= tgt) & (f.w >= tgt);
                if (__all((int)ok)) break;
                __builtin_amdgcn_s_sleep(1);
            }
            // ---- bulk h(t+1) load: 8 x 16B sc1, bf16 direct to A-frags ----
            short8 ha[8];
            #pragma unroll
            for (int j = 0; j < 8; ++j)
                ha[j] = coh_load16(hbuf + so + hoff + j * 32);
            wait_vm0();
            __builtin_amdgcn_sched_barrier(0);
            const floatx4 zero = {0.f, 0.f, 0.f, 0.f};
            floatx4 acc[4] = {zero, zero, zero, zero};
            #pragma unroll
            for (int j = 0; j < 8; ++j)
                #pragma unroll
                for (int nf = 0; nf < 4; ++nf) acc[nf] = MFMA16(ha[j], wb[j][nf], acc[nf]);
            #pragma unroll
            for (int nf = 0; nf < 4; ++nf)
                #pragma unroll
                for (int r = 0; r < 4; ++r)
                    rn[w * REDW + (kq * 4 + r) * RSTR + nf * 16 + lrow] = acc[nf][r];
        }

        if (t + 1 == T_STEPS) break;   // uniform
    }
}

extern "C" void kernel_launch(void* const* d_in, const int* in_sizes, int n_in,
                              void* d_out, int out_size, void* d_ws, size_t ws_size,
                              hipStream_t stream) {
    (void)in_sizes; (void)n_in; (void)out_size;
    const float* x      = (const float*)d_in[0];
    // d_in[1] = input_paddings (all zero, unused per reference)
    const float* kern   = (const float*)d_in[2];
    const float* bias   = (const float*)d_in[3];
    const float* h_init = (const float*)d_in[4];
    float* out = (float*)d_out;

    char* ws = (char*)d_ws;
    unsigned short* wt   = (unsigned short*)(ws);                       // 12,582,912 B
    unsigned short* xT   = (unsigned short*)(ws + 12582912);            // 33,554,432 B
    unsigned short* hbuf = (unsigned short*)(ws + 12582912 + 33554432); //    131,072 B
    int*            flags= (int*)(ws + 12582912 + 33554432 + 131072);   //      8,192 B
    (void)ws_size;

    hipFuncSetAttribute((const void*)lstm_persist,
                        hipFuncAttributeMaxDynamicSharedMemorySize, LDS_TOTAL);

    prep_wt<<<dim3(64 * 24), dim3(256), 0, stream>>>(kern, wt);
    prep_x<<<dim3(BATCH * T_STEPS / 2), dim3(256), 0, stream>>>(x, xT);
    init_h<<<dim3(33), dim3(256), 0, stream>>>(h_init, hbuf, flags);

    void* args[] = { &wt, &xT, &hbuf, &flags, &bias, &out };
    hipLaunchCooperativeKernel((const void*)lstm_persist, dim3(NBLK), dim3(512),
                               args, LDS_TOTAL, stream);
}